// Round 4
// baseline (308.384 us; speedup 1.0000x reference)
//
#include <hip/hip_runtime.h>
#include <hip/hip_cooperative_groups.h>

namespace cg = cooperative_groups;

#define BSZ  8
#define LSEQ 2048
#define DM   256
#define NS   16
#define NC   64          // chunks along L
#define LC   (LSEQ/NC)   // 32 timesteps per chunk
#define CGRP 2           // chunks handled per block (via threadIdx.x>>8)
#define TPB  512         // 256 d-lanes x 2 chunks
#define NBLK (BSZ * (NC / CGRP))   // 256 blocks -> 1 per CU, co-resident

// One fused cooperative kernel:
//   phase 1: per-(b,chunk) local scan (h0=0), x cached in registers, carry out
//   phase 2: chunk-level prefix per (b,n,d) with aL = exp(dt*A*LC), in place
//   phase 3: seeded replay from registers, y = <h,C> + D*x
// carry layout: [b][chunk][n][d]  (d contiguous -> coalesced)
__global__ __launch_bounds__(TPB, 2) void k_fused(
        const float* __restrict__ x,
        const float* __restrict__ A,
        const float* __restrict__ Bm,
        const float* __restrict__ Cm,
        const float* __restrict__ Dv,
        const float* __restrict__ delta,
        float* __restrict__ carry,
        float* __restrict__ y) {
    const int d     = threadIdx.x & (DM - 1);
    const int sub   = threadIdx.x >> 8;          // 0..CGRP-1
    const int cgp   = blockIdx.x & (NC / CGRP - 1);
    const int b     = blockIdx.x / (NC / CGRP);
    const int chunk = cgp * CGRP + sub;

    // coefficients (tables are 16 KB total -> L2-resident after first touch)
    const float dt = 1.0f / (1.0f + expf(-delta[d]));
    float a[NS], bb[NS], cc[NS];
#pragma unroll
    for (int n = 0; n < NS; ++n) {
        a[n]  = expf(dt * A[d * NS + n]);
        bb[n] = dt * Bm[d * NS + n];
        cc[n] = Cm[d * NS + n];
    }
    const float Dd = Dv[d];

    // ---- phase 1: load x chunk into registers, local scan, emit carry ----
    const size_t base = ((size_t)(b * LSEQ + chunk * LC)) * DM + d;
    const float* xp = x + base;

    float xr[LC];
#pragma unroll
    for (int t = 0; t < LC; ++t) xr[t] = xp[(size_t)t * DM];

    float h[NS];
#pragma unroll
    for (int n = 0; n < NS; ++n) h[n] = 0.0f;
#pragma unroll
    for (int t = 0; t < LC; ++t) {
        const float xv = xr[t];
#pragma unroll
        for (int n = 0; n < NS; ++n) h[n] = fmaf(a[n], h[n], bb[n] * xv);
    }
    {
        float* cp = carry + ((size_t)(b * NC + chunk) * NS) * DM + d;
#pragma unroll
        for (int n = 0; n < NS; ++n) cp[(size_t)n * DM] = h[n];
    }

    __threadfence();               // device-scope: carry visible across XCDs
    cg::this_grid().sync();

    // ---- phase 2: prefix over NC chunk carries, one thread per (b,n,d) ----
    const int tid = blockIdx.x * TPB + threadIdx.x;
    if (tid < BSZ * NS * DM) {
        const int dd = tid & (DM - 1);
        const int n2 = (tid >> 8) & (NS - 1);
        const int b2 = tid >> 12;
        const float dt2 = 1.0f / (1.0f + expf(-delta[dd]));
        const float aL  = expf(dt2 * A[dd * NS + n2] * (float)LC);
        float run = 0.0f;
        float* cp2 = carry + (size_t)b2 * NC * NS * DM + (size_t)n2 * DM + dd;
#pragma unroll
        for (int j = 0; j < NC; ++j) {
            const size_t off = (size_t)j * NS * DM;
            const float c = cp2[off];
            cp2[off] = run;                 // state entering chunk j
            run = fmaf(aL, run, c);         // state leaving chunk j
        }
    }

    __threadfence();
    cg::this_grid().sync();

    // ---- phase 3: seeded replay from registers; write y ----
    {
        const float* hp = carry + ((size_t)(b * NC + chunk) * NS) * DM + d;
#pragma unroll
        for (int n = 0; n < NS; ++n) h[n] = hp[(size_t)n * DM];
    }
    float* yp = y + base;
#pragma unroll
    for (int t = 0; t < LC; ++t) {
        const float xv = xr[t];
        float acc = Dd * xv;
#pragma unroll
        for (int n = 0; n < NS; ++n) {
            h[n] = fmaf(a[n], h[n], bb[n] * xv);
            acc  = fmaf(h[n], cc[n], acc);
        }
        yp[(size_t)t * DM] = acc;
    }
}

// ---------------------------------------------------------------------------
extern "C" void kernel_launch(void* const* d_in, const int* in_sizes, int n_in,
                              void* d_out, int out_size, void* d_ws, size_t ws_size,
                              hipStream_t stream) {
    const float* x     = (const float*)d_in[0];
    const float* A     = (const float*)d_in[1];
    const float* Bm    = (const float*)d_in[2];
    const float* Cm    = (const float*)d_in[3];
    const float* Dv    = (const float*)d_in[4];
    const float* delta = (const float*)d_in[5];
    float* y     = (float*)d_out;
    float* carry = (float*)d_ws;   // BSZ*NC*NS*DM*4 = 8 MiB scratch

    void* args[] = {(void*)&x, (void*)&A, (void*)&Bm, (void*)&Cm,
                    (void*)&Dv, (void*)&delta, (void*)&carry, (void*)&y};
    hipLaunchCooperativeKernel((void*)k_fused, dim3(NBLK), dim3(TPB),
                               args, 0, stream);
}

// Round 6
// 39.487 us; speedup vs baseline: 7.8098x; 7.8098x over previous
//
#include <hip/hip_runtime.h>

#define BSZ  8
#define LSEQ 2048
#define DM   256
#define NS   16
#define NC   128         // chunks along L  (4 waves/SIMD in passes 1 & 3)
#define LC   (LSEQ/NC)   // 16 timesteps per chunk

// ---------------------------------------------------------------------------
// Pass 1: per-(b,d,chunk) local scan with h=0 init; emit carry h_out[16].
// carry layout: [b][chunk][n][d]  (d contiguous -> coalesced)
// No register caching of x, no launch-bounds VGPR cap (round-4 lesson:
// __launch_bounds__(512,2) capped VGPR=128 -> xr[] spill -> 300 MB scratch).
// ---------------------------------------------------------------------------
__global__ void k_local(
        const float* __restrict__ x,
        const float* __restrict__ A,
        const float* __restrict__ Bm,
        const float* __restrict__ delta,
        float* __restrict__ carry) {
    const int d     = threadIdx.x;
    const int chunk = blockIdx.x & (NC - 1);
    const int b     = blockIdx.x / NC;

    const float dt = 1.0f / (1.0f + expf(-delta[d]));
    float a[NS], bb[NS];
#pragma unroll
    for (int n = 0; n < NS; ++n) {
        a[n]  = expf(dt * A[d * NS + n]);
        bb[n] = dt * Bm[d * NS + n];
    }

    float h[NS];
#pragma unroll
    for (int n = 0; n < NS; ++n) h[n] = 0.0f;

    const float* xp = x + ((size_t)(b * LSEQ + chunk * LC)) * DM + d;
#pragma unroll
    for (int t = 0; t < LC; ++t) {
        const float xv = xp[(size_t)t * DM];
#pragma unroll
        for (int n = 0; n < NS; ++n) h[n] = fmaf(a[n], h[n], bb[n] * xv);
    }

    float* cp = carry + ((size_t)(b * NC + chunk) * NS) * DM + d;
#pragma unroll
    for (int n = 0; n < NS; ++n) cp[(size_t)n * DM] = h[n];
}

// ---------------------------------------------------------------------------
// Pass 2: per-(b,n,d) sequential prefix over the NC chunk carries, in place.
// After this, carry[b][j][n][d] holds the state at the START of chunk j.
// Loads have no load->load dependency; compiler can keep many in flight.
// ---------------------------------------------------------------------------
__global__ void k_prefix(
        const float* __restrict__ A,
        const float* __restrict__ delta,
        float* __restrict__ carry) {
    const int tid = blockIdx.x * 256 + threadIdx.x;   // 0 .. BSZ*NS*DM-1
    const int d = tid & (DM - 1);
    const int n = (tid >> 8) & (NS - 1);
    const int b = tid >> 12;

    const float dt = 1.0f / (1.0f + expf(-delta[d]));
    const float aL = expf(dt * A[d * NS + n] * (float)LC);

    float run = 0.0f;
    float* cp = carry + (size_t)b * NC * NS * DM + (size_t)n * DM + d;
#pragma unroll 8
    for (int j = 0; j < NC; ++j) {
        const size_t off = (size_t)j * NS * DM;
        const float c = cp[off];
        cp[off] = run;                 // state entering chunk j
        run = fmaf(aL, run, c);        // state leaving chunk j
    }
}

// ---------------------------------------------------------------------------
// Pass 3: re-run the local scan seeded with the chunk-entry state; write y.
// y_t = <h_t, C_d> + D_d * x_t.  x re-read hits L3 (16 MB << 256 MB).
// ---------------------------------------------------------------------------
__global__ void k_final(
        const float* __restrict__ x,
        const float* __restrict__ A,
        const float* __restrict__ Bm,
        const float* __restrict__ Cm,
        const float* __restrict__ Dv,
        const float* __restrict__ delta,
        const float* __restrict__ hin,
        float* __restrict__ y) {
    const int d     = threadIdx.x;
    const int chunk = blockIdx.x & (NC - 1);
    const int b     = blockIdx.x / NC;

    const float dt = 1.0f / (1.0f + expf(-delta[d]));
    float a[NS], bb[NS], cc[NS];
#pragma unroll
    for (int n = 0; n < NS; ++n) {
        a[n]  = expf(dt * A[d * NS + n]);
        bb[n] = dt * Bm[d * NS + n];
        cc[n] = Cm[d * NS + n];
    }
    const float Dd = Dv[d];

    float h[NS];
    const float* hp = hin + ((size_t)(b * NC + chunk) * NS) * DM + d;
#pragma unroll
    for (int n = 0; n < NS; ++n) h[n] = hp[(size_t)n * DM];

    const size_t base = ((size_t)(b * LSEQ + chunk * LC)) * DM + d;
    const float* xp = x + base;
    float*       yp = y + base;
#pragma unroll
    for (int t = 0; t < LC; ++t) {
        const float xv = xp[(size_t)t * DM];
        float acc = Dd * xv;
#pragma unroll
        for (int n = 0; n < NS; ++n) {
            h[n] = fmaf(a[n], h[n], bb[n] * xv);
            acc  = fmaf(h[n], cc[n], acc);
        }
        yp[(size_t)t * DM] = acc;
    }
}

// ---------------------------------------------------------------------------
extern "C" void kernel_launch(void* const* d_in, const int* in_sizes, int n_in,
                              void* d_out, int out_size, void* d_ws, size_t ws_size,
                              hipStream_t stream) {
    const float* x     = (const float*)d_in[0];
    const float* A     = (const float*)d_in[1];
    const float* Bm    = (const float*)d_in[2];
    const float* Cm    = (const float*)d_in[3];
    const float* Dv    = (const float*)d_in[4];
    const float* delta = (const float*)d_in[5];
    float* y = (float*)d_out;

    float* carry = (float*)d_ws;   // BSZ*NC*NS*DM*4 = 16.8 MiB scratch

    dim3 blk(DM);
    dim3 grd1(BSZ * NC);                 // 1024 blocks -> 4 waves/SIMD
    k_local<<<grd1, blk, 0, stream>>>(x, A, Bm, delta, carry);

    dim3 grd2((BSZ * NS * DM) / 256);    // 128 blocks
    k_prefix<<<grd2, dim3(256), 0, stream>>>(A, delta, carry);

    k_final<<<grd1, blk, 0, stream>>>(x, A, Bm, Cm, Dv, delta, carry, y);
}

// Round 7
// 32.133 us; speedup vs baseline: 9.5972x; 1.2289x over previous
//
#include <hip/hip_runtime.h>

#define BSZ  8
#define LSEQ 2048
#define DM   256
#define NS   16
#define NC   32          // chunks along L
#define LC   (LSEQ/NC)   // 64 timesteps per chunk

// ---------------------------------------------------------------------------
// Pass 1: per-(b,d,chunk) local scan, h0=0; emit carry h_out[16].
// All LC x-loads issued into registers BEFORE any compute: 16 KB/wave in
// flight -> HBM BW-bound even at 1 wave/SIMD. No launch_bounds: VGPR demand
// ~150, must not be capped (round-4 lesson: cap at 128 -> spill -> 300 MB).
// carry layout: [b][chunk][n][d]  (d contiguous -> coalesced)
// ---------------------------------------------------------------------------
__global__ void k_local(
        const float* __restrict__ x,
        const float* __restrict__ A,
        const float* __restrict__ Bm,
        const float* __restrict__ delta,
        float* __restrict__ carry) {
    const int d     = threadIdx.x;
    const int chunk = blockIdx.x & (NC - 1);
    const int b     = blockIdx.x / NC;

    const size_t base = ((size_t)(b * LSEQ + chunk * LC)) * DM + d;
    const float* xp = x + base;

    // phase A: issue all strided x loads (lane-contiguous, 256 B/wave each)
    float xr[LC];
#pragma unroll
    for (int t = 0; t < LC; ++t) xr[t] = xp[(size_t)t * DM];

    // phase B: coefficients — transcendentals overlap the in-flight loads
    const float dt = 1.0f / (1.0f + expf(-delta[d]));
    float a[NS], bb[NS];
#pragma unroll
    for (int n = 0; n < NS; ++n) {
        a[n]  = expf(dt * A[d * NS + n]);
        bb[n] = dt * Bm[d * NS + n];
    }

    // phase C: local scan from registers
    float h[NS];
#pragma unroll
    for (int n = 0; n < NS; ++n) h[n] = 0.0f;
#pragma unroll
    for (int t = 0; t < LC; ++t) {
        const float xv = xr[t];
#pragma unroll
        for (int n = 0; n < NS; ++n) h[n] = fmaf(a[n], h[n], bb[n] * xv);
    }

    float* cp = carry + ((size_t)(b * NC + chunk) * NS) * DM + d;
#pragma unroll
    for (int n = 0; n < NS; ++n) cp[(size_t)n * DM] = h[n];
}

// ---------------------------------------------------------------------------
// Pass 2: per-(b,n,d) sequential prefix over the NC chunk carries, in place.
// After this, carry[b][j][n][d] holds the state at the START of chunk j.
// ---------------------------------------------------------------------------
__global__ void k_prefix(
        const float* __restrict__ A,
        const float* __restrict__ delta,
        float* __restrict__ carry) {
    const int tid = blockIdx.x * 256 + threadIdx.x;   // 0 .. BSZ*NS*DM-1
    const int d = tid & (DM - 1);
    const int n = (tid >> 8) & (NS - 1);
    const int b = tid >> 12;

    const float dt = 1.0f / (1.0f + expf(-delta[d]));
    const float aL = expf(dt * A[d * NS + n] * (float)LC);

    float run = 0.0f;
    float* cp = carry + (size_t)b * NC * NS * DM + (size_t)n * DM + d;
#pragma unroll
    for (int j = 0; j < NC; ++j) {
        const size_t off = (size_t)j * NS * DM;
        const float c = cp[off];
        cp[off] = run;                 // state entering chunk j
        run = fmaf(aL, run, c);        // state leaving chunk j
    }
}

// ---------------------------------------------------------------------------
// Pass 3: seeded replay; y_t = <h_t, C_d> + D_d * x_t.
// Same deep-MLP register staging of x (re-read is L3-resident).
// ---------------------------------------------------------------------------
__global__ void k_final(
        const float* __restrict__ x,
        const float* __restrict__ A,
        const float* __restrict__ Bm,
        const float* __restrict__ Cm,
        const float* __restrict__ Dv,
        const float* __restrict__ delta,
        const float* __restrict__ hin,
        float* __restrict__ y) {
    const int d     = threadIdx.x;
    const int chunk = blockIdx.x & (NC - 1);
    const int b     = blockIdx.x / NC;

    const size_t base = ((size_t)(b * LSEQ + chunk * LC)) * DM + d;
    const float* xp = x + base;

    float xr[LC];
#pragma unroll
    for (int t = 0; t < LC; ++t) xr[t] = xp[(size_t)t * DM];

    const float dt = 1.0f / (1.0f + expf(-delta[d]));
    float a[NS], bb[NS], cc[NS];
#pragma unroll
    for (int n = 0; n < NS; ++n) {
        a[n]  = expf(dt * A[d * NS + n]);
        bb[n] = dt * Bm[d * NS + n];
        cc[n] = Cm[d * NS + n];
    }
    const float Dd = Dv[d];

    float h[NS];
    const float* hp = hin + ((size_t)(b * NC + chunk) * NS) * DM + d;
#pragma unroll
    for (int n = 0; n < NS; ++n) h[n] = hp[(size_t)n * DM];

    float* yp = y + base;
#pragma unroll
    for (int t = 0; t < LC; ++t) {
        const float xv = xr[t];
        float acc = Dd * xv;
#pragma unroll
        for (int n = 0; n < NS; ++n) {
            h[n] = fmaf(a[n], h[n], bb[n] * xv);
            acc  = fmaf(h[n], cc[n], acc);
        }
        yp[(size_t)t * DM] = acc;
    }
}

// ---------------------------------------------------------------------------
extern "C" void kernel_launch(void* const* d_in, const int* in_sizes, int n_in,
                              void* d_out, int out_size, void* d_ws, size_t ws_size,
                              hipStream_t stream) {
    const float* x     = (const float*)d_in[0];
    const float* A     = (const float*)d_in[1];
    const float* Bm    = (const float*)d_in[2];
    const float* Cm    = (const float*)d_in[3];
    const float* Dv    = (const float*)d_in[4];
    const float* delta = (const float*)d_in[5];
    float* y = (float*)d_out;

    float* carry = (float*)d_ws;   // BSZ*NC*NS*DM*4 = 4.2 MiB scratch

    dim3 blk(DM);
    dim3 grd1(BSZ * NC);                 // 256 blocks
    k_local<<<grd1, blk, 0, stream>>>(x, A, Bm, delta, carry);

    dim3 grd2((BSZ * NS * DM) / 256);    // 128 blocks
    k_prefix<<<grd2, dim3(256), 0, stream>>>(A, delta, carry);

    k_final<<<grd1, blk, 0, stream>>>(x, A, Bm, Cm, Dv, delta, carry, y);
}